// Round 1
// baseline (1728.673 us; speedup 1.0000x reference)
//
#include <hip/hip_runtime.h>

// out[m,b] = sum_n M[m,n,b] * V[n,b]
// M: [2048, 2048, 64] f32 (b innermost, stride 1), V: [2048, 64], out: [2048, 64]
constexpr int M_DIM = 2048;
constexpr int N_DIM = 2048;
constexpr int BATCH = 64;
constexpr int B4    = BATCH / 4;   // 16 float4 groups across batch

__global__ __launch_bounds__(256) void batched_matvec_kernel(
    const float* __restrict__ M,
    const float* __restrict__ V,
    float* __restrict__ out)
{
    const int m    = blockIdx.x;
    const int t    = threadIdx.x;
    const int b4   = t & 15;   // which float4 group of the batch dim
    const int nsub = t >> 4;   // 0..15 : n sub-lane within a 16-row chunk

    const float4* __restrict__ Mrow =
        reinterpret_cast<const float4*>(M + (size_t)m * N_DIM * BATCH);
    const float4* __restrict__ Vv = reinterpret_cast<const float4*>(V);

    float4 acc = make_float4(0.f, 0.f, 0.f, 0.f);

    // Each iteration the block's 256 threads read M[m][n0..n0+15][0..63] = 4 KiB,
    // perfectly coalesced 16 B/lane.
    #pragma unroll 4
    for (int n0 = 0; n0 < N_DIM; n0 += 16) {
        const int n = n0 + nsub;
        const float4 mv = Mrow[n * B4 + b4];
        const float4 vv = Vv[n * B4 + b4];
        acc.x += mv.x * vv.x;
        acc.y += mv.y * vv.y;
        acc.z += mv.z * vv.z;
        acc.w += mv.w * vv.w;
    }

    // Reduce over nsub. Within a wave, the 4 lanes sharing b4 differ by 16/32.
    #pragma unroll
    for (int mask = 16; mask <= 32; mask <<= 1) {
        acc.x += __shfl_xor(acc.x, mask, 64);
        acc.y += __shfl_xor(acc.y, mask, 64);
        acc.z += __shfl_xor(acc.z, mask, 64);
        acc.w += __shfl_xor(acc.w, mask, 64);
    }

    // Cross-wave reduce: 4 waves x 16 b4 groups.
    __shared__ float4 lds[4][16];
    const int wave = t >> 6;
    const int lane = t & 63;
    if (lane < 16) lds[wave][lane] = acc;
    __syncthreads();

    if (t < 16) {
        float4 s0 = lds[0][t], s1 = lds[1][t], s2 = lds[2][t], s3 = lds[3][t];
        float4 s;
        s.x = (s0.x + s1.x) + (s2.x + s3.x);
        s.y = (s0.y + s1.y) + (s2.y + s3.y);
        s.z = (s0.z + s1.z) + (s2.z + s3.z);
        s.w = (s0.w + s1.w) + (s2.w + s3.w);
        reinterpret_cast<float4*>(out + (size_t)m * BATCH)[t] = s;
    }
}

extern "C" void kernel_launch(void* const* d_in, const int* in_sizes, int n_in,
                              void* d_out, int out_size, void* d_ws, size_t ws_size,
                              hipStream_t stream) {
    const float* M = (const float*)d_in[0];
    const float* V = (const float*)d_in[1];
    float* out = (float*)d_out;
    batched_matvec_kernel<<<dim3(M_DIM), dim3(256), 0, stream>>>(M, V, out);
}

// Round 2
// 1314.256 us; speedup vs baseline: 1.3153x; 1.3153x over previous
//
#include <hip/hip_runtime.h>

// out[m,b] = sum_n M[m,n,b] * V[n,b]
// M: [2048, 2048, 64] f32 (b innermost, stride 1), V: [2048, 64], out: [2048, 64]
constexpr int M_DIM = 2048;
constexpr int N_DIM = 2048;
constexpr int BATCH = 64;
constexpr int B4    = BATCH / 4;   // 16 float4 groups across batch
constexpr int NCHUNK = N_DIM / 16; // 128 chunks of 16 n-rows (4 KiB each)

__global__ __launch_bounds__(256) void batched_matvec_kernel(
    const float* __restrict__ M,
    const float* __restrict__ V,
    float* __restrict__ out)
{
    const int m    = blockIdx.x;
    const int t    = threadIdx.x;
    const int b4   = t & 15;   // which float4 group of the batch dim
    const int nsub = t >> 4;   // 0..15 : n sub-lane within a 16-row chunk

    const float4* __restrict__ Mrow =
        reinterpret_cast<const float4*>(M + (size_t)m * N_DIM * BATCH);
    const float4* __restrict__ Vv = reinterpret_cast<const float4*>(V);

    float4 acc = make_float4(0.f, 0.f, 0.f, 0.f);

    // Stagger each block's sweep phase through its 512 KB row so concurrent
    // blocks hit decorrelated address offsets (avoids HBM channel camping
    // from 2048 lockstep streams at 512 KB stride).
    const int phase = (m * 61) & (NCHUNK - 1);

    auto body = [&](int c) {
        const int n = c * 16 + nsub;
        const float4 mv = Mrow[n * B4 + b4];
        const float4 vv = Vv[n * B4 + b4];
        acc.x += mv.x * vv.x;
        acc.y += mv.y * vv.y;
        acc.z += mv.z * vv.z;
        acc.w += mv.w * vv.w;
    };

    #pragma unroll 4
    for (int c = phase; c < NCHUNK; ++c) body(c);
    #pragma unroll 4
    for (int c = 0; c < phase; ++c) body(c);

    // Reduce over nsub. Within a wave, the 4 lanes sharing b4 differ by 16/32.
    #pragma unroll
    for (int mask = 16; mask <= 32; mask <<= 1) {
        acc.x += __shfl_xor(acc.x, mask, 64);
        acc.y += __shfl_xor(acc.y, mask, 64);
        acc.z += __shfl_xor(acc.z, mask, 64);
        acc.w += __shfl_xor(acc.w, mask, 64);
    }

    // Cross-wave reduce: 4 waves x 16 b4 groups.
    __shared__ float4 lds[4][16];
    const int wave = t >> 6;
    const int lane = t & 63;
    if (lane < 16) lds[wave][lane] = acc;
    __syncthreads();

    if (t < 16) {
        float4 s0 = lds[0][t], s1 = lds[1][t], s2 = lds[2][t], s3 = lds[3][t];
        float4 s;
        s.x = (s0.x + s1.x) + (s2.x + s3.x);
        s.y = (s0.y + s1.y) + (s2.y + s3.y);
        s.z = (s0.z + s1.z) + (s2.z + s3.z);
        s.w = (s0.w + s1.w) + (s2.w + s3.w);
        reinterpret_cast<float4*>(out + (size_t)m * BATCH)[t] = s;
    }
}

extern "C" void kernel_launch(void* const* d_in, const int* in_sizes, int n_in,
                              void* d_out, int out_size, void* d_ws, size_t ws_size,
                              hipStream_t stream) {
    const float* M = (const float*)d_in[0];
    const float* V = (const float*)d_in[1];
    float* out = (float*)d_out;
    batched_matvec_kernel<<<dim3(M_DIM), dim3(256), 0, stream>>>(M, V, out);
}